// Round 6
// baseline (292.109 us; speedup 1.0000x reference)
//
#include <hip/hip_runtime.h>
#include <hip/hip_bf16.h>

// out[e] = relu(concat(x[src],x[dst]) @ W1 + b1) @ W2 + b2
// Phase 1: uv[n][0:256] = x[n]@W1[:256,:], uv[n][256:512] = x[n]@W1[256:,:]  (bf16)
//   Barrier-free streaming GEMM: wave holds a 64-col W1 slice in regs (asm-pinned,
//   128 VGPR), explicit 2-buffer software pipeline on the A stream.
// Phase 2: per-edge sum_k relu(uv[src][k]+uv[dst][256+k]+b1[k])*W2[k] + b2.

typedef short short8 __attribute__((ext_vector_type(8)));
typedef float f32x4 __attribute__((ext_vector_type(4)));

#define DINC 256
#define NOUTC 512

__device__ inline unsigned short f2bf(float f) {   // RNE (cold paths)
  union { float f; unsigned u; } c; c.f = f;
  unsigned u = c.u;
  return (unsigned short)((u + 0x7FFFu + ((u >> 16) & 1u)) >> 16);
}
__device__ inline float bf2f(unsigned short h) {
  union { unsigned u; float f; } c; c.u = ((unsigned)h) << 16;
  return c.f;
}
// Hot-path cvt: scalar cast -> compiler fuses pairs to v_cvt_pk_bf16_f32 (m240)
__device__ inline unsigned short fbf(float f) {
  union { __hip_bfloat16 h; unsigned short u; } c;
  c.h = __float2bfloat16(f);
  return c.u;
}

// W1t[j][k] = bf16(W1'[k][j]); j<256 -> u-half (W1 rows 0..255), j>=256 -> v-half.
__global__ void w1t_kernel(const float* __restrict__ W1, unsigned short* __restrict__ W1t) {
  int t = blockIdx.x * 256 + threadIdx.x;           // 0..131071
  int j = t >> 8, k = t & 255;
  float v = W1[(size_t)(k + ((j >= 256) ? 256 : 0)) * DINC + (j & 255)];
  W1t[(size_t)j * DINC + k] = f2bf(v);
}

// 256 thr = 4 waves, 2 blocks/CU. Wave gw: col-slice s = gw&7, stream gw>>3.
// B slice pinned in registers (asm barrier prevents rematerialization).
// A: explicit 2-buffer pipeline; 16 dense dwordx4 loads per chunk issued a full
// compute phase ahead. No LDS, no barriers.
__global__ __launch_bounds__(256, 2) void uv_gemm(const float* __restrict__ x,
                                                  const unsigned short* __restrict__ W1t,
                                                  unsigned short* __restrict__ uv,
                                                  int Nn) {
  // XCD remap: consecutive logical L on one XCD -> the 2 blocks (8 waves) of one
  // stream, and neighboring streams, share an L2 (8-slice A-reuse mostly L2-hit).
  int bpx = gridDim.x >> 3;
  int L = (blockIdx.x & 7) * bpx + (blockIdx.x >> 3);

  int lane = threadIdx.x & 63;
  int lr = lane & 15, kg = lane >> 4;
  int gw = L * 4 + (threadIdx.x >> 6);
  int s = gw & 7;                                    // col slice: s*64..s*64+63
  int n0 = s * 64;
  int stream = gw >> 3;
  int nstreams = (gridDim.x * 4) >> 3;
  int nch = (Nn + 15) >> 4;                          // 16-row chunks

  // ---- B slice -> registers (once, L2-resident W1t), then pin ----
  short8 breg[8][4];
#pragma unroll
  for (int kf = 0; kf < 8; ++kf)
#pragma unroll
    for (int nf = 0; nf < 4; ++nf)
      breg[kf][nf] = *(const short8*)(W1t + (size_t)(n0 + nf * 16 + lr) * DINC +
                                      kf * 32 + kg * 8);
#pragma unroll
  for (int kf = 0; kf < 8; ++kf)
#pragma unroll
    for (int nf = 0; nf < 4; ++nf)
      asm volatile("" : "+v"(breg[kf][nf]));   // opaque: cannot rematerialize

#define LOADA(BUF, C)                                                          \
  {                                                                            \
    int row_ = (C) * 16 + lr;                                                  \
    if (row_ >= Nn) row_ = Nn - 1;                                             \
    const float4* xp_ = (const float4*)(x + (size_t)row_ * DINC + kg * 8);     \
    _Pragma("unroll")                                                          \
    for (int kf = 0; kf < 8; ++kf) {                                           \
      BUF[2 * kf]     = xp_[kf * 8];                                           \
      BUF[2 * kf + 1] = xp_[kf * 8 + 1];                                       \
    }                                                                          \
  }

#define COMPUTE_STORE(BUF, C)                                                  \
  {                                                                            \
    f32x4 acc[4] = {};                                                         \
    _Pragma("unroll")                                                          \
    for (int kf = 0; kf < 8; ++kf) {                                           \
      float4 f0 = BUF[2 * kf], f1 = BUF[2 * kf + 1];                           \
      short8 a;                                                                \
      a[0] = (short)fbf(f0.x); a[1] = (short)fbf(f0.y);                        \
      a[2] = (short)fbf(f0.z); a[3] = (short)fbf(f0.w);                        \
      a[4] = (short)fbf(f1.x); a[5] = (short)fbf(f1.y);                        \
      a[6] = (short)fbf(f1.z); a[7] = (short)fbf(f1.w);                        \
      _Pragma("unroll")                                                        \
      for (int nf = 0; nf < 4; ++nf)                                           \
        acc[nf] = __builtin_amdgcn_mfma_f32_16x16x32_bf16(breg[kf][nf], a,     \
                                                          acc[nf], 0, 0, 0);   \
    }                                                                          \
    int row_ = (C) * 16 + lr;                                                  \
    if (row_ < Nn) {                                                           \
      unsigned short* orow_ = uv + (size_t)row_ * NOUTC + n0 + kg * 4;         \
      _Pragma("unroll")                                                        \
      for (int nf = 0; nf < 4; ++nf) {                                         \
        ushort4 pk;                                                            \
        pk.x = fbf(acc[nf][0]); pk.y = fbf(acc[nf][1]);                        \
        pk.z = fbf(acc[nf][2]); pk.w = fbf(acc[nf][3]);                        \
        *(ushort4*)(orow_ + nf * 16) = pk;                                     \
      }                                                                        \
    }                                                                          \
  }

  float4 arA[16], arB[16];
  int c = stream;
  if (c < nch) {
    LOADA(arA, c);
    for (;;) {
      int cn = c + nstreams;
      if (cn < nch) LOADA(arB, cn);       // next-chunk loads fly under compute
      COMPUTE_STORE(arA, c);
      if (cn >= nch) break;
      c = cn;
      cn = c + nstreams;
      if (cn < nch) LOADA(arA, cn);
      COMPUTE_STORE(arB, c);
      if (cn >= nch) break;
      c = cn;
    }
  }
#undef LOADA
#undef COMPUTE_STORE
}

// Quarter-wave (16 lanes) per edge: lane owns 16 of 256 channels.
__global__ __launch_bounds__(256) void edge_kernel(const int* __restrict__ eliW,
                                                   const unsigned short* __restrict__ uv,
                                                   const float* __restrict__ b1,
                                                   const float* __restrict__ W2,
                                                   const float* __restrict__ b2,
                                                   float* __restrict__ out, int E) {
  int tid = threadIdx.x;
  int ql = tid & 15;
  bool is64 = ((eliW[1] | eliW[3] | eliW[5] | eliW[7] | eliW[9] | eliW[11]) == 0);
  int shift = is64 ? 1 : 0;

  float bl[16], wl[16];
  *(float4*)(bl + 0)  = *(const float4*)(b1 + ql * 8);
  *(float4*)(bl + 4)  = *(const float4*)(b1 + ql * 8 + 4);
  *(float4*)(bl + 8)  = *(const float4*)(b1 + 128 + ql * 8);
  *(float4*)(bl + 12) = *(const float4*)(b1 + 128 + ql * 8 + 4);
  *(float4*)(wl + 0)  = *(const float4*)(W2 + ql * 8);
  *(float4*)(wl + 4)  = *(const float4*)(W2 + ql * 8 + 4);
  *(float4*)(wl + 8)  = *(const float4*)(W2 + 128 + ql * 8);
  *(float4*)(wl + 12) = *(const float4*)(W2 + 128 + ql * 8 + 4);
  float bias2 = b2[0];

  int qid = (blockIdx.x * blockDim.x + tid) >> 4;
  int nq = (gridDim.x * blockDim.x) >> 4;

  for (int e = qid; e < E; e += nq) {
    int src = eliW[((size_t)e) << shift];
    int dst = eliW[((size_t)(E + e)) << shift];
    const unsigned short* up = uv + (size_t)src * NOUTC;
    const unsigned short* vp = uv + (size_t)dst * NOUTC + DINC;
    short8 uu[2], vv[2];
    uu[0] = *(const short8*)(up + ql * 8);
    uu[1] = *(const short8*)(up + 128 + ql * 8);
    vv[0] = *(const short8*)(vp + ql * 8);
    vv[1] = *(const short8*)(vp + 128 + ql * 8);
    float s = 0.f;
#pragma unroll
    for (int g = 0; g < 2; ++g)
#pragma unroll
      for (int j = 0; j < 8; ++j) {
        float h = bf2f((unsigned short)uu[g][j]) + bf2f((unsigned short)vv[g][j]) + bl[g * 8 + j];
        s += fmaxf(h, 0.f) * wl[g * 8 + j];
      }
#pragma unroll
    for (int off = 8; off; off >>= 1) s += __shfl_xor(s, off, 64);
    if (ql == 0) out[e] = s + bias2;
  }
}

extern "C" void kernel_launch(void* const* d_in, const int* in_sizes, int n_in,
                              void* d_out, int out_size, void* d_ws, size_t ws_size,
                              hipStream_t stream) {
  const float* x   = (const float*)d_in[0];
  const int*   eli = (const int*)d_in[1];
  const float* W1  = (const float*)d_in[2];
  const float* b1  = (const float*)d_in[3];
  const float* W2  = (const float*)d_in[4];
  const float* b2  = (const float*)d_in[5];
  float* out = (float*)d_out;

  int Nn = in_sizes[0] / DINC;     // 100000
  int E  = in_sizes[1] / 2;        // 500000

  unsigned short* W1t = (unsigned short*)d_ws;              // 512*256*2 = 256 KB
  unsigned short* uv  = W1t + (size_t)NOUTC * DINC;         // Nn*512*2 ~ 102.4 MB

  w1t_kernel<<<512, 256, 0, stream>>>(W1, W1t);

  // 512 blocks x 4 waves = 2048 waves: 8 col-slices x 256 row-streams, 2 blocks/CU.
  uv_gemm<<<512, 256, 0, stream>>>(x, W1t, uv, Nn);

  edge_kernel<<<2048, 256, 0, stream>>>(eli, uv, b1, W2, b2, out, E);
}

// Round 7
// 273.298 us; speedup vs baseline: 1.0688x; 1.0688x over previous
//
#include <hip/hip_runtime.h>
#include <hip/hip_bf16.h>

// out[e] = relu(concat(x[src],x[dst]) @ W1 + b1) @ W2 + b2
// Phase 1: uv[n][0:256] = x[n]@W1[:256,:], uv[n][256:512] = x[n]@W1[256:,:]  (bf16)
//   Stream GEMM: block owns 128 uv-cols; that W1 slice lives in LDS (64 KB,
//   staged once via global_load_lds from pre-swizzled W1t, ONE barrier total).
//   Waves free-run over 32-row chunks of x; A goes straight into fragment regs.
// Phase 2: per-edge sum_k relu(uv[src][k]+uv[dst][256+k]+b1[k])*W2[k] + b2.

typedef short short8 __attribute__((ext_vector_type(8)));
typedef float f32x4 __attribute__((ext_vector_type(4)));

#define DINC 256
#define NOUTC 512

__device__ inline unsigned short f2bf(float f) {   // RNE (cold path)
  union { float f; unsigned u; } c; c.f = f;
  unsigned u = c.u;
  return (unsigned short)((u + 0x7FFFu + ((u >> 16) & 1u)) >> 16);
}
__device__ inline float bf2f(unsigned short h) {
  union { unsigned u; float f; } c; c.u = ((unsigned)h) << 16;
  return c.f;
}
// Hot-path cvt: scalar cast -> compiler fuses pairs to v_cvt_pk_bf16_f32
__device__ inline unsigned short fbf(float f) {
  union { __hip_bfloat16 h; unsigned short u; } c;
  c.h = __float2bfloat16(f);
  return c.u;
}

// Pre-swizzled W1t: col-major, 512 B per output col j; within a col the 16B
// k-chunk c=k>>3 is stored at position c ^ (j&7)  (both-sides involution so
// global_load_lds' linear copy lands pre-swizzled in LDS; read applies same XOR).
__global__ void w1t_kernel(const float* __restrict__ W1, unsigned short* __restrict__ W1t) {
  int t = blockIdx.x * 256 + threadIdx.x;           // 0..131071
  int j = t >> 8, k = t & 255;                      // j: uv col, k: input dim
  float v = W1[(size_t)(k + ((j >= 256) ? 256 : 0)) * DINC + (j & 255)];
  int sk = (((k >> 3) ^ (j & 7)) << 3) | (k & 7);
  W1t[(size_t)j * DINC + sk] = f2bf(v);
}

// 256 thr = 4 waves, 2 blocks/CU (grid 512 = persistent). Block: col-slice
// bn (128 cols), B-slice in LDS. Wave streams 32-row chunks (two 16-row
// halves, 2-buffer software pipeline in regs, ~190 VGPR).
__global__ __launch_bounds__(256, 2) void uv_gemm(const float* __restrict__ x,
                                                  const unsigned short* __restrict__ W1t,
                                                  unsigned short* __restrict__ uv,
                                                  int Nn) {
  __shared__ unsigned short Bs[128 * DINC];          // 64 KB

  // XCD remap: consecutive logical L on one XCD -> the 4 bn-slices of the same
  // rows (L with equal rank) share an XCD L2 (x fetched ~once from HBM).
  int L = (blockIdx.x & 7) * (gridDim.x >> 3) + (blockIdx.x >> 3);
  int bn = L & 3, rank = L >> 2;                     // bn: col slice, rank: row stream
  int n0 = bn * 128;

  int tid = threadIdx.x, lane = tid & 63, w = tid >> 6;
  int lr = lane & 15, kg = lane >> 4;

  // ---- stage B slice once: 64 KB linear copy (source pre-swizzled) ----
  {
    const char* wsrc = (const char*)(W1t + (size_t)n0 * DINC);
#pragma unroll
    for (int i = 0; i < 16; ++i) {
      int o = i * 4096 + w * 1024;                   // wave-uniform base
      __builtin_amdgcn_global_load_lds(
          (const __attribute__((address_space(1))) void*)(wsrc + o + lane * 16),
          (__attribute__((address_space(3))) void*)((char*)Bs + o), 16, 0, 0);
    }
  }
  __syncthreads();                                   // the only barrier

  int nch = (Nn + 31) >> 5;                          // 32-row chunks (3125)
  int stream = rank * 4 + w;                         // 0..511 per bn
  const int S = 512;                                 // streams per bn

#define LOADA(BUF, R0)                                                         \
  {                                                                            \
    int row_ = (R0) + lr;                                                      \
    if (row_ >= Nn) row_ = Nn - 1;                                             \
    const float4* xp_ = (const float4*)(x + (size_t)row_ * DINC + kg * 8);     \
    _Pragma("unroll")                                                          \
    for (int kt = 0; kt < 8; ++kt) {                                           \
      BUF[2 * kt]     = xp_[kt * 8];                                           \
      BUF[2 * kt + 1] = xp_[kt * 8 + 1];                                       \
    }                                                                          \
  }

#define CS(BUF, R0)                                                            \
  {                                                                            \
    f32x4 acc[8] = {};                                                         \
    _Pragma("unroll")                                                          \
    for (int kt = 0; kt < 8; ++kt) {                                           \
      float4 f0 = BUF[2 * kt], f1 = BUF[2 * kt + 1];                           \
      short8 a;                                                                \
      a[0] = (short)fbf(f0.x); a[1] = (short)fbf(f0.y);                        \
      a[2] = (short)fbf(f0.z); a[3] = (short)fbf(f0.w);                        \
      a[4] = (short)fbf(f1.x); a[5] = (short)fbf(f1.y);                        \
      a[6] = (short)fbf(f1.z); a[7] = (short)fbf(f1.w);                        \
      _Pragma("unroll")                                                        \
      for (int nf = 0; nf < 8; ++nf) {                                         \
        int col = nf * 16 + lr;                                                \
        short8 bf_ = *(const short8*)((char*)Bs + col * 512 +                  \
                                      (((kt * 4 + kg) ^ (lr & 7)) << 4));      \
        acc[nf] = __builtin_amdgcn_mfma_f32_16x16x32_bf16(bf_, a,              \
                                                          acc[nf], 0, 0, 0);   \
      }                                                                        \
    }                                                                          \
    int row_ = (R0) + lr;                                                      \
    if (row_ < Nn) {                                                           \
      unsigned short* orow_ = uv + (size_t)row_ * NOUTC + n0 + kg * 4;         \
      _Pragma("unroll")                                                        \
      for (int nf = 0; nf < 8; ++nf) {                                         \
        ushort4 pk;                                                            \
        pk.x = fbf(acc[nf][0]); pk.y = fbf(acc[nf][1]);                        \
        pk.z = fbf(acc[nf][2]); pk.w = fbf(acc[nf][3]);                        \
        *(ushort4*)(orow_ + nf * 16) = pk;                                     \
      }                                                                        \
    }                                                                          \
  }

  float4 A0[16], A1[16];
  int c = stream;
  if (c < nch) {
    LOADA(A0, c * 32);                               // (c, half 0)
    for (;;) {
      LOADA(A1, c * 32 + 16);                        // next half flies under CS
      CS(A0, c * 32);
      int cn = c + S;
      if (cn < nch) {
        LOADA(A0, cn * 32);
        CS(A1, c * 32 + 16);
        c = cn;
      } else {
        CS(A1, c * 32 + 16);
        break;
      }
    }
  }
#undef LOADA
#undef CS
}

// Quarter-wave (16 lanes) per edge: lane owns 16 of 256 channels.
__global__ __launch_bounds__(256) void edge_kernel(const int* __restrict__ eliW,
                                                   const unsigned short* __restrict__ uv,
                                                   const float* __restrict__ b1,
                                                   const float* __restrict__ W2,
                                                   const float* __restrict__ b2,
                                                   float* __restrict__ out, int E) {
  int tid = threadIdx.x;
  int ql = tid & 15;
  bool is64 = ((eliW[1] | eliW[3] | eliW[5] | eliW[7] | eliW[9] | eliW[11]) == 0);
  int shift = is64 ? 1 : 0;

  float bl[16], wl[16];
  *(float4*)(bl + 0)  = *(const float4*)(b1 + ql * 8);
  *(float4*)(bl + 4)  = *(const float4*)(b1 + ql * 8 + 4);
  *(float4*)(bl + 8)  = *(const float4*)(b1 + 128 + ql * 8);
  *(float4*)(bl + 12) = *(const float4*)(b1 + 128 + ql * 8 + 4);
  *(float4*)(wl + 0)  = *(const float4*)(W2 + ql * 8);
  *(float4*)(wl + 4)  = *(const float4*)(W2 + ql * 8 + 4);
  *(float4*)(wl + 8)  = *(const float4*)(W2 + 128 + ql * 8);
  *(float4*)(wl + 12) = *(const float4*)(W2 + 128 + ql * 8 + 4);
  float bias2 = b2[0];

  int qid = (blockIdx.x * blockDim.x + tid) >> 4;
  int nq = (gridDim.x * blockDim.x) >> 4;

  for (int e = qid; e < E; e += nq) {
    int src = eliW[((size_t)e) << shift];
    int dst = eliW[((size_t)(E + e)) << shift];
    const unsigned short* up = uv + (size_t)src * NOUTC;
    const unsigned short* vp = uv + (size_t)dst * NOUTC + DINC;
    short8 uu[2], vv[2];
    uu[0] = *(const short8*)(up + ql * 8);
    uu[1] = *(const short8*)(up + 128 + ql * 8);
    vv[0] = *(const short8*)(vp + ql * 8);
    vv[1] = *(const short8*)(vp + 128 + ql * 8);
    float s = 0.f;
#pragma unroll
    for (int g = 0; g < 2; ++g)
#pragma unroll
      for (int j = 0; j < 8; ++j) {
        float h = bf2f((unsigned short)uu[g][j]) + bf2f((unsigned short)vv[g][j]) + bl[g * 8 + j];
        s += fmaxf(h, 0.f) * wl[g * 8 + j];
      }
#pragma unroll
    for (int off = 8; off; off >>= 1) s += __shfl_xor(s, off, 64);
    if (ql == 0) out[e] = s + bias2;
  }
}

extern "C" void kernel_launch(void* const* d_in, const int* in_sizes, int n_in,
                              void* d_out, int out_size, void* d_ws, size_t ws_size,
                              hipStream_t stream) {
  const float* x   = (const float*)d_in[0];
  const int*   eli = (const int*)d_in[1];
  const float* W1  = (const float*)d_in[2];
  const float* b1  = (const float*)d_in[3];
  const float* W2  = (const float*)d_in[4];
  const float* b2  = (const float*)d_in[5];
  float* out = (float*)d_out;

  int Nn = in_sizes[0] / DINC;     // 100000
  int E  = in_sizes[1] / 2;        // 500000

  unsigned short* W1t = (unsigned short*)d_ws;              // 512*256*2 = 256 KB
  unsigned short* uv  = W1t + (size_t)NOUTC * DINC;         // Nn*512*2 ~ 102.4 MB

  w1t_kernel<<<512, 256, 0, stream>>>(W1, W1t);

  // 512 blocks = 2/CU persistent: 4 col-slices x 128 row-stream blocks.
  uv_gemm<<<512, 256, 0, stream>>>(x, W1t, uv, Nn);

  edge_kernel<<<2048, 256, 0, stream>>>(eli, uv, b1, W2, b2, out, E);
}

// Round 8
// 206.919 us; speedup vs baseline: 1.4117x; 1.3208x over previous
//
#include <hip/hip_runtime.h>
#include <hip/hip_bf16.h>

// out[e] = relu(concat(x[src],x[dst]) @ W1 + b1) @ W2 + b2
// Phase 0: xbf = bf16(x) stored in FRAGMENT-BLOCK order (see below).
// Phase 1: uv[n][0:256] = x[n]@W1[:256,:], uv[n][256:512] = x[n]@W1[256:,:] (bf16)
//   Stream GEMM: block owns 128 uv-cols; W1 slice in LDS frag-major (64 KB,
//   staged once, one barrier, zero-conflict linear ds_reads). Waves free-run
//   over 16-row chunks; A = 8 dense 1KB loads/chunk, reg double-buffered.
// Phase 2: per-edge sum_k relu(uv[src][k]+uv[dst][256+k]+b1[k])*W2[k] + b2.
//
// Fragment-block order: granule g holds 8 bf16 for (chunk c, kt, lane):
//   row = c*16 + (lane&15), k = kt*32 + (lane>>4)*8 + j,  g = (c*8+kt)*64+lane.

typedef short short8 __attribute__((ext_vector_type(8)));
typedef float f32x4 __attribute__((ext_vector_type(4)));

#define DINC 256
#define NOUTC 512

__device__ inline unsigned short f2bf(float f) {   // RNE
  union { float f; unsigned u; } c; c.f = f;
  unsigned u = c.u;
  return (unsigned short)((u + 0x7FFFu + ((u >> 16) & 1u)) >> 16);
}
__device__ inline float bf2f(unsigned short h) {
  union { unsigned u; float f; } c; c.u = ((unsigned)h) << 16;
  return c.f;
}
__device__ inline unsigned short fbf(float f) {    // fuses to v_cvt_pk_bf16_f32
  union { __hip_bfloat16 h; unsigned short u; } c;
  c.h = __float2bfloat16(f);
  return c.u;
}

// W1t frag-major: t = granule id in [0,16384): bn=t>>12, kt=(t>>9)&7,
// nf=(t>>6)&7, lane=t&63 -> col = bn*128+nf*16+(lane&15),
// k = kt*32+(lane>>4)*8+j.  W1'[k][col] = col<256 ? W1[k][col] : W1[256+k][col-256].
__global__ void w1t_kernel(const float* __restrict__ W1, unsigned short* __restrict__ W1t) {
  int t = blockIdx.x * 256 + threadIdx.x;           // 0..16383
  int lane = t & 63, nf = (t >> 6) & 7, kt = (t >> 9) & 7, bn = t >> 12;
  int col = bn * 128 + nf * 16 + (lane & 15);
  int k0 = kt * 32 + (lane >> 4) * 8;
  int off = (col >= 256) ? 256 : 0;
  int cs = col & 255;
  short8 v;
#pragma unroll
  for (int j = 0; j < 8; ++j)
    v[j] = (short)f2bf(W1[(size_t)(k0 + j + off) * DINC + cs]);
  *(short8*)(W1t + (size_t)t * 8) = v;
}

// xbf producer: thread = granule g in [0, (Nn/16)*512): c=g>>9, kt=(g>>6)&7,
// lane=g&63. Reads 8 fp32 from x, writes dense 16B granule.
__global__ __launch_bounds__(256) void cvt_kernel(const float* __restrict__ x,
                                                  unsigned short* __restrict__ xbf,
                                                  int Nn) {
  int g = blockIdx.x * 256 + threadIdx.x;
  int lane = g & 63, kt = (g >> 6) & 7, c = g >> 9;
  int row = c * 16 + (lane & 15);
  if (row >= Nn) row = Nn - 1;
  int k0 = kt * 32 + (lane >> 4) * 8;
  const float4* xp = (const float4*)(x + (size_t)row * DINC + k0);
  float4 f0 = xp[0], f1 = xp[1];
  short8 v;
  v[0] = (short)fbf(f0.x); v[1] = (short)fbf(f0.y);
  v[2] = (short)fbf(f0.z); v[3] = (short)fbf(f0.w);
  v[4] = (short)fbf(f1.x); v[5] = (short)fbf(f1.y);
  v[6] = (short)fbf(f1.z); v[7] = (short)fbf(f1.w);
  *(short8*)(xbf + (size_t)g * 8) = v;
}

// 256 thr = 4 waves, 2 blocks/CU, grid 512 persistent.
// Block: bn col-slice (128 cols), B in LDS frag-major. Wave: 16r x 128c chunks.
__global__ __launch_bounds__(256, 2) void uv_gemm(const unsigned short* __restrict__ xbf,
                                                  const unsigned short* __restrict__ W1t,
                                                  unsigned short* __restrict__ uv,
                                                  int Nn) {
  __shared__ unsigned short Bs[128 * DINC];          // 64 KB frag-major

  // XCD remap: the 4 bn-slices of the same rank co-resident on one XCD L2.
  int L = (blockIdx.x & 7) * (gridDim.x >> 3) + (blockIdx.x >> 3);
  int bn = L & 3, rank = L >> 2;

  int tid = threadIdx.x, lane = tid & 63, w = tid >> 6;
  int lr = lane & 15, kg = lane >> 4;

  // ---- stage B slice once (linear 64 KB copy, frag-major source) ----
  {
    const char* bsrc = (const char*)W1t + (size_t)bn * 65536;
#pragma unroll
    for (int i = 0; i < 16; ++i) {
      int o = i * 4096 + w * 1024;                   // wave-uniform base
      __builtin_amdgcn_global_load_lds(
          (const __attribute__((address_space(1))) void*)(bsrc + o + lane * 16),
          (__attribute__((address_space(3))) void*)((char*)Bs + o), 16, 0, 0);
    }
  }
  __syncthreads();                                   // the only barrier

  int nch = (Nn + 15) >> 4;                          // 6250
  int stream = rank * 4 + w;                         // 0..511
  const int S = 512;
  const char* xb = (const char*)xbf;

#define LOADH(BUF, C)                                                          \
  {                                                                            \
    const char* p_ = xb + (size_t)(C) * 8192 + lane * 16;                      \
    _Pragma("unroll")                                                          \
    for (int kt = 0; kt < 8; ++kt)                                             \
      BUF[kt] = *(const short8*)(p_ + kt * 1024);                              \
  }

#define CS(BUF, C)                                                             \
  {                                                                            \
    f32x4 acc[8] = {};                                                         \
    _Pragma("unroll")                                                          \
    for (int kt = 0; kt < 8; ++kt) {                                           \
      _Pragma("unroll")                                                        \
      for (int nf = 0; nf < 8; ++nf) {                                         \
        short8 bf_ = *(const short8*)((char*)Bs + ((kt * 8 + nf) * 64 + lane) * 16); \
        acc[nf] = __builtin_amdgcn_mfma_f32_16x16x32_bf16(bf_, BUF[kt],        \
                                                          acc[nf], 0, 0, 0);   \
      }                                                                        \
    }                                                                          \
    int row_ = (C) * 16 + lr;                                                  \
    if (row_ < Nn) {                                                           \
      unsigned short* orow_ = uv + (size_t)row_ * NOUTC + bn * 128 + kg * 4;   \
      _Pragma("unroll")                                                        \
      for (int nf = 0; nf < 8; ++nf) {                                         \
        ushort4 pk;                                                            \
        pk.x = fbf(acc[nf][0]); pk.y = fbf(acc[nf][1]);                        \
        pk.z = fbf(acc[nf][2]); pk.w = fbf(acc[nf][3]);                        \
        *(ushort4*)(orow_ + nf * 16) = pk;                                     \
      }                                                                        \
    }                                                                          \
  }

  short8 A0[8], A1[8];
  int c = stream;
  if (c < nch) {
    LOADH(A0, c);
    for (;;) {
      int c1 = c + S;
      if (c1 < nch) {
        LOADH(A1, c1);                               // next chunk under compute
        CS(A0, c);
        int c2 = c1 + S;
        if (c2 < nch) {
          LOADH(A0, c2);
          CS(A1, c1);
          c = c2;
        } else { CS(A1, c1); break; }
      } else { CS(A0, c); break; }
    }
  }
#undef LOADH
#undef CS
}

// Quarter-wave (16 lanes) per edge: lane owns 16 of 256 channels.
__global__ __launch_bounds__(256) void edge_kernel(const int* __restrict__ eliW,
                                                   const unsigned short* __restrict__ uv,
                                                   const float* __restrict__ b1,
                                                   const float* __restrict__ W2,
                                                   const float* __restrict__ b2,
                                                   float* __restrict__ out, int E) {
  int tid = threadIdx.x;
  int ql = tid & 15;
  bool is64 = ((eliW[1] | eliW[3] | eliW[5] | eliW[7] | eliW[9] | eliW[11]) == 0);
  int shift = is64 ? 1 : 0;

  float bl[16], wl[16];
  *(float4*)(bl + 0)  = *(const float4*)(b1 + ql * 8);
  *(float4*)(bl + 4)  = *(const float4*)(b1 + ql * 8 + 4);
  *(float4*)(bl + 8)  = *(const float4*)(b1 + 128 + ql * 8);
  *(float4*)(bl + 12) = *(const float4*)(b1 + 128 + ql * 8 + 4);
  *(float4*)(wl + 0)  = *(const float4*)(W2 + ql * 8);
  *(float4*)(wl + 4)  = *(const float4*)(W2 + ql * 8 + 4);
  *(float4*)(wl + 8)  = *(const float4*)(W2 + 128 + ql * 8);
  *(float4*)(wl + 12) = *(const float4*)(W2 + 128 + ql * 8 + 4);
  float bias2 = b2[0];

  int qid = (blockIdx.x * blockDim.x + tid) >> 4;
  int nq = (gridDim.x * blockDim.x) >> 4;

  for (int e = qid; e < E; e += nq) {
    int src = eliW[((size_t)e) << shift];
    int dst = eliW[((size_t)(E + e)) << shift];
    const unsigned short* up = uv + (size_t)src * NOUTC;
    const unsigned short* vp = uv + (size_t)dst * NOUTC + DINC;
    short8 uu[2], vv[2];
    uu[0] = *(const short8*)(up + ql * 8);
    uu[1] = *(const short8*)(up + 128 + ql * 8);
    vv[0] = *(const short8*)(vp + ql * 8);
    vv[1] = *(const short8*)(vp + 128 + ql * 8);
    float s = 0.f;
#pragma unroll
    for (int g = 0; g < 2; ++g)
#pragma unroll
      for (int j = 0; j < 8; ++j) {
        float h = bf2f((unsigned short)uu[g][j]) + bf2f((unsigned short)vv[g][j]) + bl[g * 8 + j];
        s += fmaxf(h, 0.f) * wl[g * 8 + j];
      }
#pragma unroll
    for (int off = 8; off; off >>= 1) s += __shfl_xor(s, off, 64);
    if (ql == 0) out[e] = s + bias2;
  }
}

extern "C" void kernel_launch(void* const* d_in, const int* in_sizes, int n_in,
                              void* d_out, int out_size, void* d_ws, size_t ws_size,
                              hipStream_t stream) {
  const float* x   = (const float*)d_in[0];
  const int*   eli = (const int*)d_in[1];
  const float* W1  = (const float*)d_in[2];
  const float* b1  = (const float*)d_in[3];
  const float* W2  = (const float*)d_in[4];
  const float* b2  = (const float*)d_in[5];
  float* out = (float*)d_out;

  int Nn = in_sizes[0] / DINC;     // 100000
  int E  = in_sizes[1] / 2;        // 500000
  int nch = (Nn + 15) >> 4;        // 6250

  unsigned short* W1t = (unsigned short*)d_ws;              // 256 KB (frag-major)
  unsigned short* uv  = W1t + (size_t)NOUTC * DINC;         // ~102.4 MB
  unsigned short* xbf = uv + (size_t)Nn * NOUTC;            // ~51.2 MB (frag-block)

  w1t_kernel<<<64, 256, 0, stream>>>(W1, W1t);
  cvt_kernel<<<nch * 2, 256, 0, stream>>>(x, xbf, Nn);      // nch*512 granules / 256

  // 512 blocks = 2/CU persistent: 4 col-slices x 128 ranks.
  uv_gemm<<<512, 256, 0, stream>>>(xbf, W1t, uv, Nn);

  edge_kernel<<<2048, 256, 0, stream>>>(eli, uv, b1, W2, b2, out, E);
}

// Round 9
// 153.092 us; speedup vs baseline: 1.9081x; 1.3516x over previous
//
#include <hip/hip_runtime.h>
#include <hip/hip_bf16.h>

// out[e] = relu(concat(x[src],x[dst]) @ W1 + b1) @ W2 + b2
// Phase 0: xbf = bf16(x) stored in FRAGMENT-BLOCK order (see below).
// Phase 1: uv[n][0:256] = x[n]@W1[:256,:], uv[n][256:512] = x[n]@W1[256:,:] (bf16)
//   Stream GEMM: block owns 128 uv-cols; W1 slice in LDS frag-major (64 KB,
//   staged once, one barrier, zero-conflict linear ds_reads). Waves free-run
//   over 16-row chunks; A = 8 dense 1KB loads/chunk, reg double-buffered.
// Phase 2: per-edge sum_k relu(uv[src][k]+uv[dst][256+k]+b1[k])*W2[k] + b2.
//
// Fragment-block order: granule g holds 8 bf16 for (chunk c, kt, lane):
//   row = c*16 + (lane&15), k = kt*32 + (lane>>4)*8 + j,  g = (c*8+kt)*64+lane.

typedef short short8 __attribute__((ext_vector_type(8)));
typedef float f32x4 __attribute__((ext_vector_type(4)));

#define DINC 256
#define NOUTC 512

__device__ inline unsigned short f2bf(float f) {   // RNE
  union { float f; unsigned u; } c; c.f = f;
  unsigned u = c.u;
  return (unsigned short)((u + 0x7FFFu + ((u >> 16) & 1u)) >> 16);
}
__device__ inline float bf2f(unsigned short h) {
  union { unsigned u; float f; } c; c.u = ((unsigned)h) << 16;
  return c.f;
}
__device__ inline unsigned short fbf(float f) {    // fuses to v_cvt_pk_bf16_f32
  union { __hip_bfloat16 h; unsigned short u; } c;
  c.h = __float2bfloat16(f);
  return c.u;
}

// W1t frag-major: t = granule id in [0,16384): bn=t>>12, kt=(t>>9)&7,
// nf=(t>>6)&7, lane=t&63 -> col = bn*128+nf*16+(lane&15),
// k = kt*32+(lane>>4)*8+j.  W1'[k][col] = col<256 ? W1[k][col] : W1[256+k][col-256].
__global__ void w1t_kernel(const float* __restrict__ W1, unsigned short* __restrict__ W1t) {
  int t = blockIdx.x * 256 + threadIdx.x;           // 0..16383
  int lane = t & 63, nf = (t >> 6) & 7, kt = (t >> 9) & 7, bn = t >> 12;
  int col = bn * 128 + nf * 16 + (lane & 15);
  int k0 = kt * 32 + (lane >> 4) * 8;
  int off = (col >= 256) ? 256 : 0;
  int cs = col & 255;
  short8 v;
#pragma unroll
  for (int j = 0; j < 8; ++j)
    v[j] = (short)f2bf(W1[(size_t)(k0 + j + off) * DINC + cs]);
  *(short8*)(W1t + (size_t)t * 8) = v;
}

// xbf producer: thread = granule g in [0, (Nn/16)*512): c=g>>9, kt=(g>>6)&7,
// lane=g&63. Reads 8 fp32 from x, writes dense 16B granule.
__global__ __launch_bounds__(256) void cvt_kernel(const float* __restrict__ x,
                                                  unsigned short* __restrict__ xbf,
                                                  int Nn) {
  int g = blockIdx.x * 256 + threadIdx.x;
  int lane = g & 63, kt = (g >> 6) & 7, c = g >> 9;
  int row = c * 16 + (lane & 15);
  if (row >= Nn) row = Nn - 1;
  int k0 = kt * 32 + (lane >> 4) * 8;
  const float4* xp = (const float4*)(x + (size_t)row * DINC + k0);
  float4 f0 = xp[0], f1 = xp[1];
  short8 v;
  v[0] = (short)fbf(f0.x); v[1] = (short)fbf(f0.y);
  v[2] = (short)fbf(f0.z); v[3] = (short)fbf(f0.w);
  v[4] = (short)fbf(f1.x); v[5] = (short)fbf(f1.y);
  v[6] = (short)fbf(f1.z); v[7] = (short)fbf(f1.w);
  *(short8*)(xbf + (size_t)g * 8) = v;
}

// 256 thr = 4 waves, 2 blocks/CU (LDS-limited), grid 512 persistent.
// Block: bn col-slice (128 cols), B in LDS frag-major. Wave: 16r x 128c chunks.
// launch_bounds min-waves = 1: let the allocator take ~150-180 VGPR for the
// full pipeline live set (<=256 keeps 2 waves/SIMD = exactly our residency).
__global__ __launch_bounds__(256, 1) void uv_gemm(const unsigned short* __restrict__ xbf,
                                                  const unsigned short* __restrict__ W1t,
                                                  unsigned short* __restrict__ uv,
                                                  int Nn) {
  __shared__ unsigned short Bs[128 * DINC];          // 64 KB frag-major

  // XCD remap: the 4 bn-slices of the same rank co-resident on one XCD L2.
  int L = (blockIdx.x & 7) * (gridDim.x >> 3) + (blockIdx.x >> 3);
  int bn = L & 3, rank = L >> 2;

  int tid = threadIdx.x, lane = tid & 63, w = tid >> 6;
  int lr = lane & 15, kg = lane >> 4;

  // ---- stage B slice once (linear 64 KB copy, frag-major source) ----
  {
    const char* bsrc = (const char*)W1t + (size_t)bn * 65536;
#pragma unroll
    for (int i = 0; i < 16; ++i) {
      int o = i * 4096 + w * 1024;                   // wave-uniform base
      __builtin_amdgcn_global_load_lds(
          (const __attribute__((address_space(1))) void*)(bsrc + o + lane * 16),
          (__attribute__((address_space(3))) void*)((char*)Bs + o), 16, 0, 0);
    }
  }
  __syncthreads();                                   // the only barrier

  int nch = (Nn + 15) >> 4;                          // 6250
  int stream = rank * 4 + w;                         // 0..511
  const int S = 512;
  const char* xb = (const char*)xbf;

#define LOADH(BUF, C)                                                          \
  {                                                                            \
    const char* p_ = xb + (size_t)(C) * 8192 + lane * 16;                      \
    _Pragma("unroll")                                                          \
    for (int kt = 0; kt < 8; ++kt)                                             \
      BUF[kt] = *(const short8*)(p_ + kt * 1024);                              \
  }

#define CS(BUF, C)                                                             \
  {                                                                            \
    f32x4 acc[8] = {};                                                         \
    _Pragma("unroll")                                                          \
    for (int kt = 0; kt < 8; ++kt) {                                           \
      _Pragma("unroll")                                                        \
      for (int nf = 0; nf < 8; ++nf) {                                         \
        short8 bf_ = *(const short8*)((char*)Bs + ((kt * 8 + nf) * 64 + lane) * 16); \
        acc[nf] = __builtin_amdgcn_mfma_f32_16x16x32_bf16(bf_, BUF[kt],        \
                                                          acc[nf], 0, 0, 0);   \
      }                                                                        \
    }                                                                          \
    int row_ = (C) * 16 + lr;                                                  \
    if (row_ < Nn) {                                                           \
      unsigned short* orow_ = uv + (size_t)row_ * NOUTC + bn * 128 + kg * 4;   \
      _Pragma("unroll")                                                        \
      for (int nf = 0; nf < 8; ++nf) {                                         \
        ushort4 pk;                                                            \
        pk.x = fbf(acc[nf][0]); pk.y = fbf(acc[nf][1]);                        \
        pk.z = fbf(acc[nf][2]); pk.w = fbf(acc[nf][3]);                        \
        *(ushort4*)(orow_ + nf * 16) = pk;                                     \
      }                                                                        \
    }                                                                          \
  }

  short8 A0[8], A1[8];
  int c = stream;
  if (c < nch) {
    LOADH(A0, c);
    for (;;) {
      int c1 = c + S;
      if (c1 < nch) {
        LOADH(A1, c1);                               // next chunk under compute
        CS(A0, c);
        int c2 = c1 + S;
        if (c2 < nch) {
          LOADH(A0, c2);
          CS(A1, c1);
          c = c2;
        } else { CS(A1, c1); break; }
      } else { CS(A0, c); break; }
    }
  }
#undef LOADH
#undef CS
}

// Quarter-wave (16 lanes) per edge: lane owns 16 of 256 channels.
__global__ __launch_bounds__(256) void edge_kernel(const int* __restrict__ eliW,
                                                   const unsigned short* __restrict__ uv,
                                                   const float* __restrict__ b1,
                                                   const float* __restrict__ W2,
                                                   const float* __restrict__ b2,
                                                   float* __restrict__ out, int E) {
  int tid = threadIdx.x;
  int ql = tid & 15;
  bool is64 = ((eliW[1] | eliW[3] | eliW[5] | eliW[7] | eliW[9] | eliW[11]) == 0);
  int shift = is64 ? 1 : 0;

  float bl[16], wl[16];
  *(float4*)(bl + 0)  = *(const float4*)(b1 + ql * 8);
  *(float4*)(bl + 4)  = *(const float4*)(b1 + ql * 8 + 4);
  *(float4*)(bl + 8)  = *(const float4*)(b1 + 128 + ql * 8);
  *(float4*)(bl + 12) = *(const float4*)(b1 + 128 + ql * 8 + 4);
  *(float4*)(wl + 0)  = *(const float4*)(W2 + ql * 8);
  *(float4*)(wl + 4)  = *(const float4*)(W2 + ql * 8 + 4);
  *(float4*)(wl + 8)  = *(const float4*)(W2 + 128 + ql * 8);
  *(float4*)(wl + 12) = *(const float4*)(W2 + 128 + ql * 8 + 4);
  float bias2 = b2[0];

  int qid = (blockIdx.x * blockDim.x + tid) >> 4;
  int nq = (gridDim.x * blockDim.x) >> 4;

  for (int e = qid; e < E; e += nq) {
    int src = eliW[((size_t)e) << shift];
    int dst = eliW[((size_t)(E + e)) << shift];
    const unsigned short* up = uv + (size_t)src * NOUTC;
    const unsigned short* vp = uv + (size_t)dst * NOUTC + DINC;
    short8 uu[2], vv[2];
    uu[0] = *(const short8*)(up + ql * 8);
    uu[1] = *(const short8*)(up + 128 + ql * 8);
    vv[0] = *(const short8*)(vp + ql * 8);
    vv[1] = *(const short8*)(vp + 128 + ql * 8);
    float s = 0.f;
#pragma unroll
    for (int g = 0; g < 2; ++g)
#pragma unroll
      for (int j = 0; j < 8; ++j) {
        float h = bf2f((unsigned short)uu[g][j]) + bf2f((unsigned short)vv[g][j]) + bl[g * 8 + j];
        s += fmaxf(h, 0.f) * wl[g * 8 + j];
      }
#pragma unroll
    for (int off = 8; off; off >>= 1) s += __shfl_xor(s, off, 64);
    if (ql == 0) out[e] = s + bias2;
  }
}

extern "C" void kernel_launch(void* const* d_in, const int* in_sizes, int n_in,
                              void* d_out, int out_size, void* d_ws, size_t ws_size,
                              hipStream_t stream) {
  const float* x   = (const float*)d_in[0];
  const int*   eli = (const int*)d_in[1];
  const float* W1  = (const float*)d_in[2];
  const float* b1  = (const float*)d_in[3];
  const float* W2  = (const float*)d_in[4];
  const float* b2  = (const float*)d_in[5];
  float* out = (float*)d_out;

  int Nn = in_sizes[0] / DINC;     // 100000
  int E  = in_sizes[1] / 2;        // 500000
  int nch = (Nn + 15) >> 4;        // 6250

  unsigned short* W1t = (unsigned short*)d_ws;              // 256 KB (frag-major)
  unsigned short* uv  = W1t + (size_t)NOUTC * DINC;         // ~102.4 MB
  unsigned short* xbf = uv + (size_t)Nn * NOUTC;            // ~51.2 MB (frag-block)

  w1t_kernel<<<64, 256, 0, stream>>>(W1, W1t);
  cvt_kernel<<<nch * 2, 256, 0, stream>>>(x, xbf, Nn);      // nch*512 granules / 256

  // 512 blocks = 2/CU persistent: 4 col-slices x 128 ranks.
  uv_gemm<<<512, 256, 0, stream>>>(xbf, W1t, uv, Nn);

  edge_kernel<<<2048, 256, 0, stream>>>(eli, uv, b1, W2, b2, out, E);
}